// Round 3
// baseline (364.864 us; speedup 1.0000x reference)
//
#include <hip/hip_runtime.h>
#include <math.h>

#define N_QUBITS 24
#define N_BLOCKS 4
#define NSTATE (1 << N_QUBITS)

// Qubit q <-> flat-index bit (23 - q)  (row-major reshape of (2,)*24).
// Per block, gates reordered (valid by commutation) into the staircase:
//   RY(0); for q=1..23: RY(q); CNOT(q-1, q)
// split into 2 register-resident passes:
//   P1R: qubits 0..8   -> bits 15..23  (2 LDS transposes)
//   P23: qubits 9..23  -> bits 0..14   (3 LDS transposes; CNOT(8,9) ctrl = bit 15)
// Block 0's P1R is replaced by an in-LDS 9-qubit simulation fused into P23 (init).

// LDS swizzle: XOR bits 6..10 and 11..14 into bank bits 0..4.
// Every transpose pattern used below is <=2-way on 32 banks (free, m136).
#define SWZ(e) ((e) ^ (((e) >> 6) & 31) ^ (((e) >> 11) & 31))

// RY on reg bit 5 (pairs r, r|32), then conditional swap (CNOT with external ctrl).
__device__ __forceinline__ void pair_top(float (&a)[64], float s, float c, int swap) {
#pragma unroll
    for (int r = 0; r < 32; ++r) {
        float v0 = a[r], v1 = a[r | 32];
        float o0 = c * v0 - s * v1;
        float o1 = s * v0 + c * v1;
        a[r]      = swap ? o1 : o0;
        a[r | 32] = swap ? o0 : o1;
    }
}

// Fused RY(tgt = reg bit BT) then CNOT(ctrl = reg bit BT+1, tgt = reg bit BT).
template <int BT>
__device__ __forceinline__ void quad_gate(float (&a)[64], float s, float c) {
#pragma unroll
    for (int g = 0; g < 16; ++g) {
        int lo  = g & ((1 << BT) - 1);
        int r00 = ((g >> BT) << (BT + 2)) | lo;
        int r01 = r00 | (1 << BT);
        int r10 = r00 | (2 << BT);
        int r11 = r00 | (3 << BT);
        float v00 = a[r00], v01 = a[r01], v10 = a[r10], v11 = a[r11];
        a[r00] = c * v00 - s * v01;
        a[r01] = s * v00 + c * v01;
        a[r10] = s * v10 + c * v11;   // ctrl=1 half: RY then swap (CNOT)
        a[r11] = c * v10 - s * v11;
    }
}

// ---------------- Pass 1 (register-resident): qubits 0..8 (bits 15..23) ---------
// 512 threads, 64 regs/thread = 32768 floats: bits 15..23 (gates) x bits 0..5.
// blockIdx = bits 6..14. Phase A: regs = e18..23, w = e15..17, lane = e0..5.
// Phase B (after T1): regs = e15..17 (bits 3..5) + e0..2 (bits 0..2),
//                     lane = e18..23, w = e3..5.
__global__ __launch_bounds__(512)
void pass1r_kernel(float* __restrict__ state, const float* __restrict__ angles, int blk_b) {
    __shared__ float lds[32768];
    const int tid  = threadIdx.x;
    const int lane = tid & 63;
    const int w    = tid >> 6;
    const int blk  = blockIdx.x;                 // e6..14
    const float* ang = angles + blk_b * N_QUBITS;
    const size_t lowbase = ((size_t)blk << 6) | (size_t)lane;

    float a[64];
#pragma unroll
    for (int r = 0; r < 64; ++r)
        a[r] = state[((size_t)((r << 3) | w) << 15) | lowbase];

    float s, c;
    // phase A: qubits 0..5 on reg bits 5..0 (e23..e18)
    sincosf(0.5f * ang[0], &s, &c); pair_top(a, s, c, 0);
    sincosf(0.5f * ang[1], &s, &c); quad_gate<4>(a, s, c);
    sincosf(0.5f * ang[2], &s, &c); quad_gate<3>(a, s, c);
    sincosf(0.5f * ang[3], &s, &c); quad_gate<2>(a, s, c);
    sincosf(0.5f * ang[4], &s, &c); quad_gate<1>(a, s, c);
    sincosf(0.5f * ang[5], &s, &c); quad_gate<0>(a, s, c);

    // T1: phase-A h=(r<<9)|(w<<6)|lane -> phase-B h=(lane<<9)|(rhi<<6)|(w<<3)|rlo
#pragma unroll
    for (int r = 0; r < 64; ++r) {
        int h = (r << 9) | (w << 6) | lane;
        lds[SWZ(h)] = a[r];
    }
    __syncthreads();
#pragma unroll
    for (int r = 0; r < 64; ++r) {
        int h = (lane << 9) | ((r >> 3) << 6) | (w << 3) | (r & 7);
        a[r] = lds[SWZ(h)];
    }

    // phase B: qubit 6 (tgt e17 = reg bit 5, ctrl e18 = lane bit 0),
    //          qubit 7 (quad on reg bits 5,4), qubit 8 (quad on reg bits 4,3).
    sincosf(0.5f * ang[6], &s, &c); pair_top(a, s, c, lane & 1);
    sincosf(0.5f * ang[7], &s, &c); quad_gate<4>(a, s, c);
    sincosf(0.5f * ang[8], &s, &c); quad_gate<3>(a, s, c);

    // T2: back to load layout
    __syncthreads();
#pragma unroll
    for (int r = 0; r < 64; ++r) {
        int h = (lane << 9) | ((r >> 3) << 6) | (w << 3) | (r & 7);
        lds[SWZ(h)] = a[r];
    }
    __syncthreads();
#pragma unroll
    for (int r = 0; r < 64; ++r) {
        int h = (r << 9) | (w << 6) | lane;
        a[r] = lds[SWZ(h)];
    }

#pragma unroll
    for (int r = 0; r < 64; ++r)
        state[((size_t)((r << 3) | w) << 15) | lowbase] = a[r];
}

// ---------------- Pass 2+3 tail: qubits 9..23 on a 32768-float chunk -----------
// Entry layout: regs = e9..14, w = e6..8, lane = e0..5 (a[] already populated).
template <bool SQUARE>
__device__ __forceinline__ void p23_tail(float (&a)[64], float* __restrict__ lds,
                                         float* __restrict__ base, const float* ang,
                                         int lane, int w, int c15) {
    float s, c;
    // phase 1: qubits 9..14 on reg bits (e9..14)
    sincosf(0.5f * ang[9], &s, &c);  pair_top(a, s, c, c15);        // RY(9)+CNOT(8,9)
    sincosf(0.5f * ang[10], &s, &c); quad_gate<4>(a, s, c);
    sincosf(0.5f * ang[11], &s, &c); quad_gate<3>(a, s, c);
    sincosf(0.5f * ang[12], &s, &c); quad_gate<2>(a, s, c);
    sincosf(0.5f * ang[13], &s, &c); quad_gate<1>(a, s, c);
    sincosf(0.5f * ang[14], &s, &c); quad_gate<0>(a, s, c);

    // T1: -> regs = e3..8, lanes = e9..14, w = e0..2
#pragma unroll
    for (int r = 0; r < 64; ++r) {
        int e = (r << 9) | (w << 6) | lane;
        lds[SWZ(e)] = a[r];
    }
    __syncthreads();
#pragma unroll
    for (int r = 0; r < 64; ++r) {
        int e = (lane << 9) | (r << 3) | w;
        a[r] = lds[SWZ(e)];
    }

    // phase 2: qubits 15..20 on reg bits (e3..8)
    sincosf(0.5f * ang[15], &s, &c); pair_top(a, s, c, lane & 1);   // ctrl e9
    sincosf(0.5f * ang[16], &s, &c); quad_gate<4>(a, s, c);
    sincosf(0.5f * ang[17], &s, &c); quad_gate<3>(a, s, c);
    sincosf(0.5f * ang[18], &s, &c); quad_gate<2>(a, s, c);
    sincosf(0.5f * ang[19], &s, &c); quad_gate<1>(a, s, c);
    sincosf(0.5f * ang[20], &s, &c); quad_gate<0>(a, s, c);

    // T2: -> regs = e0..5, lanes = e6..11, w = e12..14
    __syncthreads();
#pragma unroll
    for (int r = 0; r < 64; ++r) {
        int e = (lane << 9) | (r << 3) | w;
        lds[SWZ(e)] = a[r];
    }
    __syncthreads();
#pragma unroll
    for (int r = 0; r < 64; ++r) {
        int e = (w << 12) | (lane << 6) | r;
        a[r] = lds[SWZ(e)];
    }

    // phase 3: qubits 21..23 on reg bits (e0..2, ctrl e3 in regs)
    sincosf(0.5f * ang[21], &s, &c); quad_gate<2>(a, s, c);
    sincosf(0.5f * ang[22], &s, &c); quad_gate<1>(a, s, c);
    sincosf(0.5f * ang[23], &s, &c); quad_gate<0>(a, s, c);

    if (SQUARE) {
#pragma unroll
        for (int r = 0; r < 64; ++r) a[r] *= a[r];
    }

    // T3: -> regs = e6..11, lanes = e0..5, w = e12..14 (store layout)
    __syncthreads();
#pragma unroll
    for (int r = 0; r < 64; ++r) {
        int e = (w << 12) | (lane << 6) | r;
        lds[SWZ(e)] = a[r];
    }
    __syncthreads();
#pragma unroll
    for (int r = 0; r < 64; ++r) {
        int e = (w << 12) | (r << 6) | lane;
        a[r] = lds[SWZ(e)];
    }

#pragma unroll
    for (int r = 0; r < 64; ++r)
        base[(w << 12) | (r << 6) | lane] = a[r];
}

template <bool SQUARE>
__global__ __launch_bounds__(512)
void pass23_kernel(float* __restrict__ state, const float* __restrict__ angles, int blk_b) {
    __shared__ float lds[32768];
    const int tid  = threadIdx.x;
    const int lane = tid & 63;
    const int w    = tid >> 6;
    const int chunk = blockIdx.x;                // e15..23
    float* __restrict__ base = state + ((size_t)chunk << 15);
    const int c15 = chunk & 1;
    const float* ang = angles + blk_b * N_QUBITS;

    float a[64];
#pragma unroll
    for (int r = 0; r < 64; ++r)
        a[r] = base[(r << 9) | (w << 6) | lane];

    p23_tail<SQUARE>(a, lds, base, ang, lane, w, c15);
}

// Block 0 fused: after qubits 0..8 from |0..0>, state = f9[bits15..23] * delta(bits0..14).
// Compute the 512-amplitude f9 in LDS, seed a[], then run the normal 9..23 tail.
__global__ __launch_bounds__(512)
void pass23_init_kernel(float* __restrict__ state, const float* __restrict__ angles) {
    __shared__ float lds[32768];
    const int tid  = threadIdx.x;
    const int lane = tid & 63;
    const int w    = tid >> 6;
    const int chunk = blockIdx.x;
    float* __restrict__ base = state + ((size_t)chunk << 15);
    const float* ang = angles;                   // block 0
    float s, c;

    // f9: 9-qubit staircase; f9 index bit k = global bit 15+k; qubit q -> bit 8-q
    float* f = lds;
    f[tid] = 0.0f;
    if (tid >= 512) {}                           // blockDim == 512
    __syncthreads();
    if (tid == 0) f[0] = 1.0f;
    __syncthreads();
    sincosf(0.5f * ang[0], &s, &c);
    if (tid < 256) {
        float v0 = f[tid], v1 = f[tid | 256];
        f[tid]       = c * v0 - s * v1;
        f[tid | 256] = s * v0 + c * v1;
    }
    __syncthreads();
    for (int q = 1; q <= 8; ++q) {
        sincosf(0.5f * ang[q], &s, &c);
        int bt = 8 - q;
        if (tid < 128) {
            int lo  = tid & ((1 << bt) - 1);
            int r00 = ((tid >> bt) << (bt + 2)) | lo;
            int r01 = r00 | (1 << bt);
            int r10 = r00 | (2 << bt);
            int r11 = r00 | (3 << bt);
            float v00 = f[r00], v01 = f[r01], v10 = f[r10], v11 = f[r11];
            f[r00] = c * v00 - s * v01;
            f[r01] = s * v00 + c * v01;
            f[r10] = s * v10 + c * v11;
            f[r11] = c * v10 - s * v11;
        }
        __syncthreads();
    }
    const float amp = f[chunk];
    __syncthreads();                             // lds reused by the tail

    float a[64];
#pragma unroll
    for (int r = 0; r < 64; ++r) a[r] = 0.0f;
    if (tid == 0) a[0] = amp;                    // h = 0 -> r = 0, w = 0, lane = 0

    p23_tail<false>(a, lds, base, ang, lane, w, chunk & 1);
}

extern "C" void kernel_launch(void* const* d_in, const int* in_sizes, int n_in,
                              void* d_out, int out_size, void* d_ws, size_t ws_size,
                              hipStream_t stream) {
    const float* angles = (const float*)d_in[0];
    float* state = (float*)d_out;   // state lives in d_out; last pass squares in place

    pass23_init_kernel<<<NSTATE >> 15, 512, 0, stream>>>(state, angles);

    for (int b = 1; b < N_BLOCKS; ++b) {
        pass1r_kernel<<<NSTATE >> 15, 512, 0, stream>>>(state, angles, b);
        if (b == N_BLOCKS - 1)
            pass23_kernel<true><<<NSTATE >> 15, 512, 0, stream>>>(state, angles, b);
        else
            pass23_kernel<false><<<NSTATE >> 15, 512, 0, stream>>>(state, angles, b);
    }
}

// Round 5
// 262.907 us; speedup vs baseline: 1.3878x; 1.3878x over previous
//
#include <hip/hip_runtime.h>
#include <math.h>

#define N_QUBITS 24
#define N_BLOCKS 4
#define NSTATE (1 << N_QUBITS)

// Qubit q <-> flat-index bit (23 - q)  (row-major reshape of (2,)*24).
// Per block, gates reordered (valid by commutation) into the staircase:
//   RY(0); for q=1..23: RY(q); CNOT(q-1, q)
// Fast path (needs ws_size >= 64 MiB): ping-pong buffers, alternating layouts.
//   standard layout: addr = e23..e0
//   pi layout:       addr = e[6..14]<<15 | H<<6 | e[0..5],  H bit k = e(15+k)
//   P1  (qubits 0..8):  reads d_out standard (scattered 256B reads),
//                       writes d_ws pi (CONTIGUOUS 128 KiB/wg)
//   P23 (qubits 9..23): reads d_ws pi (scattered 256B reads),
//                       writes d_out standard (CONTIGUOUS)
// Race-free because read buffer != write buffer (R4's in-place version raced).
// Block 0 is replaced by pass23_init (in-LDS 9-qubit sim + tail) -> d_out.
// Fallback path: proven in-place kernels (R1 pass1 tile + R2 pass23).

// LDS swizzle for the tail transposes (verified conflict-free in R2/R3).
#define SWZ(e) ((e) ^ (((e) >> 6) & 31) ^ (((e) >> 11) & 31))

// RY on reg bit B (pairs r, r|1<<B), then conditional swap (CNOT w/ external ctrl).
template <int B>
__device__ __forceinline__ void pair_bit(float (&a)[64], float s, float c, int swap) {
#pragma unroll
    for (int g = 0; g < 32; ++g) {
        int r0 = ((g >> B) << (B + 1)) | (g & ((1 << B) - 1));
        int r1 = r0 | (1 << B);
        float v0 = a[r0], v1 = a[r1];
        float o0 = c * v0 - s * v1;
        float o1 = s * v0 + c * v1;
        a[r0] = swap ? o1 : o0;
        a[r1] = swap ? o0 : o1;
    }
}
__device__ __forceinline__ void pair_top(float (&a)[64], float s, float c, int swap) {
    pair_bit<5>(a, s, c, swap);
}

// Fused RY(tgt = reg bit BT) then CNOT(ctrl = reg bit BT+1, tgt = reg bit BT).
template <int BT>
__device__ __forceinline__ void quad_gate(float (&a)[64], float s, float c) {
#pragma unroll
    for (int g = 0; g < 16; ++g) {
        int lo  = g & ((1 << BT) - 1);
        int r00 = ((g >> BT) << (BT + 2)) | lo;
        int r01 = r00 | (1 << BT);
        int r10 = r00 | (2 << BT);
        int r11 = r00 | (3 << BT);
        float v00 = a[r00], v01 = a[r01], v10 = a[r10], v11 = a[r11];
        a[r00] = c * v00 - s * v01;
        a[r01] = s * v00 + c * v01;
        a[r10] = s * v10 + c * v11;   // ctrl=1 half: RY then swap (CNOT)
        a[r11] = c * v10 - s * v11;
    }
}

// ================= FAST PATH =================
// ---------------- Pass 1 (std -> pi): qubits 0..8 (bits 15..23) ----------------
// 512 threads x 64 regs = 32768 floats: bits 15..23 x bits 0..5; blk = e6..14.
// Phase A: regs = e18..23 (bit i = e18+i), w = e15..17, lane = e0..5.
// Phase B: regs r' = (e23, e17, e16, e15, e22, e21) bits 5..0, w = e18..20.
// T1 chunked by e23 (reg bit 5 both phases): 2 rounds x 16K floats = 64 KiB LDS.
__global__ __launch_bounds__(512)
void pass1_pi_kernel(const float* __restrict__ src, float* __restrict__ dst,
                     const float* __restrict__ angles, int blk_b) {
    __shared__ float lds[16384];
    const int tid  = threadIdx.x;
    const int lane = tid & 63;
    const int w    = tid >> 6;
    const int blk  = blockIdx.x;                 // e6..14
    const float* ang = angles + blk_b * N_QUBITS;
    const size_t lowbase = ((size_t)blk << 6) | (size_t)lane;

    float a[64];
    // read standard: 256-B segments at 128-KiB stride (no write amplification risk)
#pragma unroll
    for (int r = 0; r < 64; ++r)
        a[r] = src[((size_t)((r << 3) | w) << 15) | lowbase];

    float s, c;
    // phase A: qubits 0..5 on e23..e18 = reg bits 5..0
    sincosf(0.5f * ang[0], &s, &c); pair_top(a, s, c, 0);
    sincosf(0.5f * ang[1], &s, &c); quad_gate<4>(a, s, c);
    sincosf(0.5f * ang[2], &s, &c); quad_gate<3>(a, s, c);
    sincosf(0.5f * ang[3], &s, &c); quad_gate<2>(a, s, c);
    sincosf(0.5f * ang[4], &s, &c); quad_gate<1>(a, s, c);
    sincosf(0.5f * ang[5], &s, &c); quad_gate<0>(a, s, c);

    // T1 (within-chunk h bits: h13..h6 = e22,e21,e20,e19,e18,e17,e16,e15; h5..h0 = lane)
#pragma unroll
    for (int cb = 0; cb < 2; ++cb) {
        if (cb) __syncthreads();
#pragma unroll
        for (int rr = 0; rr < 32; ++rr)
            lds[(rr << 9) | (w << 6) | lane] = a[(cb << 5) | rr];
        __syncthreads();
#pragma unroll
        for (int q = 0; q < 32; ++q) {
            int h = (((q >> 1) & 1) << 13) | ((q & 1) << 12) | (w << 9)
                  | (((q >> 4) & 1) << 8) | (((q >> 3) & 1) << 7) | (((q >> 2) & 1) << 6)
                  | lane;
            a[(cb << 5) | q] = lds[h];
        }
    }

    // phase B: qubit 6 (tgt e17 = r' bit 4, ctrl e18 = w&1), qubit 7 (quad 4,3),
    //          qubit 8 (quad 3,2)
    sincosf(0.5f * ang[6], &s, &c); pair_bit<4>(a, s, c, w & 1);
    sincosf(0.5f * ang[7], &s, &c); quad_gate<3>(a, s, c);
    sincosf(0.5f * ang[8], &s, &c); quad_gate<2>(a, s, c);

    // store pi: H = (r'5<<8)|(r'1<<7)|(r'0<<6)|(w<<3)|(r'4<<2)|(r'3<<1)|r'2
    // -> workgroup writes contiguous [blk<<15, blk<<15 + 32768)
#pragma unroll
    for (int r = 0; r < 64; ++r) {
        int H = (((r >> 5) & 1) << 8) | (((r >> 1) & 1) << 7) | ((r & 1) << 6) | (w << 3)
              | (((r >> 4) & 1) << 2) | (((r >> 3) & 1) << 1) | ((r >> 2) & 1);
        dst[((size_t)blk << 15) | (H << 6) | lane] = a[r];
    }
}

// ---------------- Pass 2+3 tail: qubits 9..23 on a 32768-float chunk -----------
// Entry layout: regs = e9..14, w = e6..8, lane = e0..5. Writes STANDARD layout.
template <bool SQUARE>
__device__ __forceinline__ void p23_tail(float (&a)[64], float* __restrict__ lds,
                                         float* __restrict__ base, const float* ang,
                                         int lane, int w, int c15) {
    float s, c;
    // phase 1: qubits 9..14 on reg bits (e9..14)
    sincosf(0.5f * ang[9], &s, &c);  pair_top(a, s, c, c15);        // RY(9)+CNOT(8,9)
    sincosf(0.5f * ang[10], &s, &c); quad_gate<4>(a, s, c);
    sincosf(0.5f * ang[11], &s, &c); quad_gate<3>(a, s, c);
    sincosf(0.5f * ang[12], &s, &c); quad_gate<2>(a, s, c);
    sincosf(0.5f * ang[13], &s, &c); quad_gate<1>(a, s, c);
    sincosf(0.5f * ang[14], &s, &c); quad_gate<0>(a, s, c);

    // T1: -> regs = e3..8, lanes = e9..14, w = e0..2
#pragma unroll
    for (int r = 0; r < 64; ++r) {
        int e = (r << 9) | (w << 6) | lane;
        lds[SWZ(e)] = a[r];
    }
    __syncthreads();
#pragma unroll
    for (int r = 0; r < 64; ++r) {
        int e = (lane << 9) | (r << 3) | w;
        a[r] = lds[SWZ(e)];
    }

    // phase 2: qubits 15..20 on reg bits (e3..8)
    sincosf(0.5f * ang[15], &s, &c); pair_top(a, s, c, lane & 1);   // ctrl e9
    sincosf(0.5f * ang[16], &s, &c); quad_gate<4>(a, s, c);
    sincosf(0.5f * ang[17], &s, &c); quad_gate<3>(a, s, c);
    sincosf(0.5f * ang[18], &s, &c); quad_gate<2>(a, s, c);
    sincosf(0.5f * ang[19], &s, &c); quad_gate<1>(a, s, c);
    sincosf(0.5f * ang[20], &s, &c); quad_gate<0>(a, s, c);

    // T2: -> regs = e0..5, lanes = e6..11, w = e12..14
    __syncthreads();
#pragma unroll
    for (int r = 0; r < 64; ++r) {
        int e = (lane << 9) | (r << 3) | w;
        lds[SWZ(e)] = a[r];
    }
    __syncthreads();
#pragma unroll
    for (int r = 0; r < 64; ++r) {
        int e = (w << 12) | (lane << 6) | r;
        a[r] = lds[SWZ(e)];
    }

    // phase 3: qubits 21..23 on reg bits (e0..2, ctrl e3 in regs)
    sincosf(0.5f * ang[21], &s, &c); quad_gate<2>(a, s, c);
    sincosf(0.5f * ang[22], &s, &c); quad_gate<1>(a, s, c);
    sincosf(0.5f * ang[23], &s, &c); quad_gate<0>(a, s, c);

    if (SQUARE) {
#pragma unroll
        for (int r = 0; r < 64; ++r) a[r] *= a[r];
    }

    // T3: -> regs = e6..11, lanes = e0..5, w = e12..14 (store layout)
    __syncthreads();
#pragma unroll
    for (int r = 0; r < 64; ++r) {
        int e = (w << 12) | (lane << 6) | r;
        lds[SWZ(e)] = a[r];
    }
    __syncthreads();
#pragma unroll
    for (int r = 0; r < 64; ++r) {
        int e = (w << 12) | (r << 6) | lane;
        a[r] = lds[SWZ(e)];
    }

    // store STANDARD: contiguous 128-KiB workgroup footprint
#pragma unroll
    for (int r = 0; r < 64; ++r)
        base[(w << 12) | (r << 6) | lane] = a[r];
}

// P23 fast: read pi from src, write standard to dst.
template <bool SQUARE>
__global__ __launch_bounds__(512)
void pass23_pi_kernel(const float* __restrict__ src, float* __restrict__ dst,
                      const float* __restrict__ angles, int blk_b) {
    __shared__ float lds[32768];
    const int tid  = threadIdx.x;
    const int lane = tid & 63;
    const int w    = tid >> 6;
    const int chunk = blockIdx.x;                // = H = e15..23
    float* __restrict__ base = dst + ((size_t)chunk << 15);
    const int c15 = chunk & 1;                   // e15
    const float* ang = angles + blk_b * N_QUBITS;

    float a[64];
    // read pi: addr = (r<<3|w)<<15 | chunk<<6 | lane -> e6..8 = w, e9..14 = r, e0..5 = lane
#pragma unroll
    for (int r = 0; r < 64; ++r)
        a[r] = src[((size_t)((r << 3) | w) << 15) | ((size_t)chunk << 6) | (size_t)lane];

    p23_tail<SQUARE>(a, lds, base, ang, lane, w, c15);
}

// Block 0 fused: after qubits 0..8 from |0..0>, state = f9[e15..23] * delta(e0..14).
// Compute the 512-amplitude f9 in LDS, seed a[], run the 9..23 tail. Writes STANDARD.
__global__ __launch_bounds__(512)
void pass23_init_kernel(float* __restrict__ dst, const float* __restrict__ angles) {
    __shared__ float lds[32768];
    const int tid  = threadIdx.x;
    const int lane = tid & 63;
    const int w    = tid >> 6;
    const int chunk = blockIdx.x;
    float* __restrict__ base = dst + ((size_t)chunk << 15);
    const float* ang = angles;                   // block 0
    float s, c;

    float* f = lds;
    f[tid] = 0.0f;
    __syncthreads();
    if (tid == 0) f[0] = 1.0f;
    __syncthreads();
    sincosf(0.5f * ang[0], &s, &c);
    if (tid < 256) {
        float v0 = f[tid], v1 = f[tid | 256];
        f[tid]       = c * v0 - s * v1;
        f[tid | 256] = s * v0 + c * v1;
    }
    __syncthreads();
    for (int q = 1; q <= 8; ++q) {
        sincosf(0.5f * ang[q], &s, &c);
        int bt = 8 - q;
        if (tid < 128) {
            int lo  = tid & ((1 << bt) - 1);
            int r00 = ((tid >> bt) << (bt + 2)) | lo;
            int r01 = r00 | (1 << bt);
            int r10 = r00 | (2 << bt);
            int r11 = r00 | (3 << bt);
            float v00 = f[r00], v01 = f[r01], v10 = f[r10], v11 = f[r11];
            f[r00] = c * v00 - s * v01;
            f[r01] = s * v00 + c * v01;
            f[r10] = s * v10 + c * v11;
            f[r11] = c * v10 - s * v11;
        }
        __syncthreads();
    }
    const float amp = f[chunk];
    __syncthreads();                             // lds reused by the tail

    float a[64];
#pragma unroll
    for (int r = 0; r < 64; ++r) a[r] = 0.0f;
    if (tid == 0) a[0] = amp;                    // index 0 -> r = 0, w = 0, lane = 0

    p23_tail<false>(a, lds, base, ang, lane, w, chunk & 1);
}

// ================= FALLBACK (in-place, race-free: read set == write set) =======
__global__ __launch_bounds__(256)
void pass1_fb_kernel(float* __restrict__ state, const float* __restrict__ angles, int blk_b) {
    __shared__ float tile[512][17];
    const int tid = threadIdx.x;
    const int base_low = blockIdx.x << 4;

    for (int r0 = 0; r0 < 512; r0 += 16) {
        int row = r0 + (tid >> 4), col = tid & 15;
        tile[row][col] = state[base_low + col + (row << 15)];
    }
    __syncthreads();

    const float* ang = angles + blk_b * N_QUBITS;
    {
        float s, c;
        sincosf(0.5f * ang[0], &s, &c);
        for (int i = tid; i < 4096; i += 256) {
            int col = i & 15, pr = i >> 4;
            float v0 = tile[pr][col], v1 = tile[pr + 256][col];
            tile[pr][col]       = c * v0 - s * v1;
            tile[pr + 256][col] = s * v0 + c * v1;
        }
        __syncthreads();
    }
    for (int q = 1; q <= 8; ++q) {
        float s, c;
        sincosf(0.5f * ang[q], &s, &c);
        int bt = 8 - q;
        for (int i = tid; i < 2048; i += 256) {
            int col = i & 15, qr = i >> 4;
            int low = qr & ((1 << bt) - 1);
            int r00 = ((qr >> bt) << (bt + 2)) | low;
            int r01 = r00 | (1 << bt);
            int r10 = r00 | (2 << bt);
            int r11 = r00 | (3 << bt);
            float v00 = tile[r00][col], v01 = tile[r01][col];
            float v10 = tile[r10][col], v11 = tile[r11][col];
            tile[r00][col] = c * v00 - s * v01;
            tile[r01][col] = s * v00 + c * v01;
            tile[r10][col] = s * v10 + c * v11;
            tile[r11][col] = c * v10 - s * v11;
        }
        __syncthreads();
    }
    for (int r0 = 0; r0 < 512; r0 += 16) {
        int row = r0 + (tid >> 4), col = tid & 15;
        state[base_low + col + (row << 15)] = tile[row][col];
    }
}

template <bool SQUARE>
__global__ __launch_bounds__(512)
void pass23_fb_kernel(float* __restrict__ state, const float* __restrict__ angles, int blk_b) {
    __shared__ float lds[32768];
    const int tid  = threadIdx.x;
    const int lane = tid & 63;
    const int w    = tid >> 6;
    const int chunk = blockIdx.x;
    float* __restrict__ base = state + ((size_t)chunk << 15);
    const int c15 = chunk & 1;
    const float* ang = angles + blk_b * N_QUBITS;

    float a[64];
#pragma unroll
    for (int r = 0; r < 64; ++r)
        a[r] = base[(r << 9) | (w << 6) | lane];

    p23_tail<SQUARE>(a, lds, base, ang, lane, w, c15);
}

extern "C" void kernel_launch(void* const* d_in, const int* in_sizes, int n_in,
                              void* d_out, int out_size, void* d_ws, size_t ws_size,
                              hipStream_t stream) {
    const float* angles = (const float*)d_in[0];
    float* out = (float*)d_out;
    float* ws  = (float*)d_ws;
    const bool fast = ws_size >= (size_t)NSTATE * sizeof(float);

    pass23_init_kernel<<<NSTATE >> 15, 512, 0, stream>>>(out, angles);

    for (int b = 1; b < N_BLOCKS; ++b) {
        const bool last = (b == N_BLOCKS - 1);
        if (fast) {
            pass1_pi_kernel<<<NSTATE >> 15, 512, 0, stream>>>(out, ws, angles, b);
            if (last)
                pass23_pi_kernel<true><<<NSTATE >> 15, 512, 0, stream>>>(ws, out, angles, b);
            else
                pass23_pi_kernel<false><<<NSTATE >> 15, 512, 0, stream>>>(ws, out, angles, b);
        } else {
            pass1_fb_kernel<<<2048, 256, 0, stream>>>(out, angles, b);
            if (last)
                pass23_fb_kernel<true><<<NSTATE >> 15, 512, 0, stream>>>(out, angles, b);
            else
                pass23_fb_kernel<false><<<NSTATE >> 15, 512, 0, stream>>>(out, angles, b);
        }
    }
}